// Round 1
// baseline (3971.712 us; speedup 1.0000x reference)
//
#include <hip/hip_runtime.h>

typedef unsigned short u16;
typedef unsigned int   u32;
typedef __bf16 bf16x8 __attribute__((ext_vector_type(8)));
typedef float  f32x4  __attribute__((ext_vector_type(4)));
typedef unsigned short u16x4 __attribute__((ext_vector_type(4)));
typedef unsigned short u16x8 __attribute__((ext_vector_type(8)));

#define DEV __device__ __forceinline__

DEV u16 f2b(float f) {                      // f32 -> bf16 RNE
  u32 u = __builtin_bit_cast(u32, f);
  return (u16)((u + 0x7fffu + ((u >> 16) & 1u)) >> 16);
}
DEV float b2f(u16 h) { u32 u = ((u32)h) << 16; return __builtin_bit_cast(float, u); }

DEV void gload16(const void* g, void* l) {  // async global->LDS, 16B/lane
  __builtin_amdgcn_global_load_lds((__attribute__((address_space(1))) void*)(g),
                                   (__attribute__((address_space(3))) void*)(l),
                                   16, 0, 0);
}

DEV f32x4 MFMA(bf16x8 a, bf16x8 b, f32x4 c) {
  return __builtin_amdgcn_mfma_f32_16x16x32_bf16(a, b, c, 0, 0, 0);
}

// ---------------------------------------------------------------- transpose+cvt
// W[K][N] f32 (row-major) -> Wt[N][K] bf16
__global__ __launch_bounds__(256) void transpose_cvt(const float* __restrict__ W,
                                                     u16* __restrict__ Wt,
                                                     int K, int N) {
  __shared__ float tile[32][33];
  const int n0 = blockIdx.x * 32, k0 = blockIdx.y * 32;
  const int tx = threadIdx.x, ty = threadIdx.y;  // 32 x 8
#pragma unroll
  for (int i = 0; i < 32; i += 8)
    tile[ty + i][tx] = W[(size_t)(k0 + ty + i) * N + n0 + tx];
  __syncthreads();
#pragma unroll
  for (int i = 0; i < 32; i += 8)
    Wt[(size_t)(n0 + ty + i) * K + k0 + tx] = f2b(tile[tx][ty + i]);
}

// ---------------------------------------------------------------- rmsnorm (f32 in, bf16 out), D=4096
__global__ __launch_bounds__(256) void rmsnorm_k(const float* __restrict__ x,
                                                 const float* __restrict__ w,
                                                 u16* __restrict__ o, int D) {
  const int row = blockIdx.x, tid = threadIdx.x;
  const float4* xr = (const float4*)(x + (size_t)row * D);
  const float4* wr = (const float4*)w;
  float4 v[4];
  float ss = 0.f;
#pragma unroll
  for (int i = 0; i < 4; ++i) {
    v[i] = xr[i * 256 + tid];
    ss += v[i].x * v[i].x + v[i].y * v[i].y + v[i].z * v[i].z + v[i].w * v[i].w;
  }
#pragma unroll
  for (int off = 1; off < 64; off <<= 1) ss += __shfl_xor(ss, off, 64);
  __shared__ float red[4];
  if ((tid & 63) == 0) red[tid >> 6] = ss;
  __syncthreads();
  const float tot = red[0] + red[1] + red[2] + red[3];
  const float sc = rsqrtf(tot / (float)D + 1e-6f);
  u16x4* orow = (u16x4*)(o + (size_t)row * D);
#pragma unroll
  for (int i = 0; i < 4; ++i) {
    float4 wv = wr[i * 256 + tid];
    u16x4 p;
    p[0] = f2b(v[i].x * sc * wv.x);
    p[1] = f2b(v[i].y * sc * wv.y);
    p[2] = f2b(v[i].z * sc * wv.z);
    p[3] = f2b(v[i].w * sc * wv.w);
    orow[i * 256 + tid] = p;
  }
}

// ---------------------------------------------------------------- RoPE table: cos at tab[bs*64+i], sin at tab[BS*64 + bs*64+i]
__global__ __launch_bounds__(256) void rope_table(const int* __restrict__ positions,
                                                  float* __restrict__ tab, int BS) {
  const int idx = blockIdx.x * 256 + threadIdx.x;
  if (idx >= BS * 64) return;
  const int bs = idx >> 6, i = idx & 63;
  const float pos = (float)positions[bs];
  const float inv = __expf(-(float)i * (9.210340371976184f / 64.f));  // 10000^(-i/64)
  const float ang = pos * inv;
  float s, c;
  sincosf(ang, &s, &c);
  tab[idx] = c;
  tab[BS * 64 + idx] = s;
}

// ---------------------------------------------------------------- RoPE in-place on bf16 qkv [BS][12288]
__global__ __launch_bounds__(256) void rope_apply(u16* __restrict__ qkv,
                                                  const float* __restrict__ tab, int BS) {
  const int idx = blockIdx.x * 256 + threadIdx.x;  // (bs, h, i)
  if (idx >= BS * 2048) return;
  const int i = idx & 63, h = (idx >> 6) & 31, bs = idx >> 11;
  const float c = tab[bs * 64 + i];
  const float s = tab[(size_t)BS * 64 + bs * 64 + i];
  const size_t base = (size_t)bs * 12288 + h * 128 + i;
  float x1 = b2f(qkv[base]), x2 = b2f(qkv[base + 64]);
  qkv[base] = f2b(x1 * c - x2 * s);
  qkv[base + 64] = f2b(x2 * c + x1 * s);
  float y1 = b2f(qkv[base + 4096]), y2 = b2f(qkv[base + 4096 + 64]);
  qkv[base + 4096] = f2b(y1 * c - y2 * s);
  qkv[base + 4096 + 64] = f2b(y2 * c + y1 * s);
}

// ---------------------------------------------------------------- GEMM: C[M,N] = A[M,K] * Bt[N,K]^T (+epilogue)
// MODE 0: bf16 out         MODE 1: bf16 out + f32 bias[col]
// MODE 2: f32 out + f32 residual[idx]
// MODE 3: bf16 out = g1[idx] * silu(acc)   (in-place over g1 allowed)
template <int MODE>
__global__ __launch_bounds__(256) void gemm_bt(const u16* __restrict__ A,
                                               const u16* __restrict__ Bt,
                                               void* __restrict__ outp,
                                               const float* __restrict__ bias,
                                               const float* __restrict__ resid,
                                               const u16* __restrict__ g1,
                                               int M, int N, int K) {
  __shared__ __align__(16) u16 As[128 * 32];
  __shared__ __align__(16) u16 Bs[128 * 32];
  const int tid = threadIdx.x;
  const int w = tid >> 6, l = tid & 63;
  const int wm = w >> 1, wn = w & 1;
  const int lr = l & 15, lc = l >> 4;
  const int m0 = blockIdx.y * 128, n0 = blockIdx.x * 128;
  f32x4 acc[4][4] = {};
  const int nk = K >> 5;
  const int srow = tid >> 2, scol = (tid & 3) * 8;
  const u16* Ag = A + (size_t)(m0 + srow) * K + scol;
  const u16* Bg = Bt + (size_t)(n0 + srow) * K + scol;
  u16* AsB0 = &As[(w * 16) * 32];
  u16* AsB1 = &As[(64 + w * 16) * 32];
  u16* BsB0 = &Bs[(w * 16) * 32];
  u16* BsB1 = &Bs[(64 + w * 16) * 32];

  for (int kt = 0; kt < nk; ++kt) {
    const int k0 = kt << 5;
    gload16(Ag + k0, AsB0);
    gload16(Ag + (size_t)64 * K + k0, AsB1);
    gload16(Bg + k0, BsB0);
    gload16(Bg + (size_t)64 * K + k0, BsB1);
    __syncthreads();
    bf16x8 af[4], bfr[4];
#pragma unroll
    for (int f = 0; f < 4; ++f)
      af[f] = *(const bf16x8*)&As[(wm * 64 + f * 16 + lr) * 32 + 8 * lc];
#pragma unroll
    for (int f = 0; f < 4; ++f)
      bfr[f] = *(const bf16x8*)&Bs[(wn * 64 + f * 16 + lr) * 32 + 8 * lc];
#pragma unroll
    for (int i = 0; i < 4; ++i)
#pragma unroll
      for (int j = 0; j < 4; ++j) acc[i][j] = MFMA(af[i], bfr[j], acc[i][j]);
    __syncthreads();
  }

#pragma unroll
  for (int i = 0; i < 4; ++i) {
#pragma unroll
    for (int j = 0; j < 4; ++j) {
      const int gr = m0 + wm * 64 + i * 16 + lc * 4;
      const int gc = n0 + wn * 64 + j * 16 + lr;
#pragma unroll
      for (int r = 0; r < 4; ++r) {
        float v = acc[i][j][r];
        const size_t idx = (size_t)(gr + r) * N + gc;
        if constexpr (MODE == 0) {
          ((u16*)outp)[idx] = f2b(v);
        } else if constexpr (MODE == 1) {
          ((u16*)outp)[idx] = f2b(v + bias[gc]);
        } else if constexpr (MODE == 2) {
          ((float*)outp)[idx] = v + resid[idx];
        } else {
          const float g = b2f(g1[idx]);
          const float sv = v / (1.f + __expf(-v));
          ((u16*)outp)[idx] = f2b(g * sv);
        }
      }
    }
  }
}

// ---------------------------------------------------------------- flash attention (causal), HD=128
// qkv bf16 [B*S][12288]: Q at h*128, K at 4096+h*128, V at 8192+h*128
// out bf16 [B*S][4096] at h*128
__global__ __launch_bounds__(256) void attn_kernel(const u16* __restrict__ qkv,
                                                   u16* __restrict__ o, int S) {
  const int qt = blockIdx.x, bh = blockIdx.y;
  const int b = bh >> 5, h = bh & 31;
  const int q0 = qt * 64;
  const int tid = threadIdx.x;
  const int w = tid >> 6, l = tid & 63;
  const int lr = l & 15, lc = l >> 4;
  const size_t RS = 12288;
  const float SCALE = 0.08838834764831845f;  // 128^-0.5

  __shared__ __align__(16) u16 Ks[32 * 128];   // [k][d]
  __shared__ __align__(16) u16 Vt[128 * 32];   // [d][k]
  __shared__ __align__(16) u16 Ps[4][16 * 32]; // per-wave P [i][k]

  // Q fragments: row = q0 + w*16 + lr, k-dim elems kc*32 + 8*lc + j
  bf16x8 qf[4];
  {
    const u16* qp = qkv + (size_t)(b * S + q0 + w * 16 + lr) * RS + h * 128 + 8 * lc;
#pragma unroll
    for (int kc = 0; kc < 4; ++kc) qf[kc] = *(const bf16x8*)(qp + kc * 32);
  }

  float m_[4], ls[4];
  f32x4 O[8] = {};
#pragma unroll
  for (int r = 0; r < 4; ++r) { m_[r] = -3e38f; ls[r] = 0.f; }

  const int nkt = qt * 2 + 2;  // keys up to q0+63
  for (int kt = 0; kt < nkt; ++kt) {
    const int k0 = kt * 32;
    // stage K (global_load_lds, linear) and V (transposed via regs)
#pragma unroll
    for (int it = 0; it < 2; ++it) {
      const int eid = it * 256 + tid;
      const int kr = eid >> 4, d0 = (eid & 15) * 8;
      gload16(qkv + (size_t)(b * S + k0 + kr) * RS + 4096 + h * 128 + d0,
              &Ks[(it * 256 + w * 64) * 8]);
    }
#pragma unroll
    for (int it = 0; it < 2; ++it) {
      const int eid = it * 256 + tid;
      const int vr = eid >> 4, d0 = (eid & 15) * 8;
      u16x8 v8 = *(const u16x8*)(qkv + (size_t)(b * S + k0 + vr) * RS + 8192 + h * 128 + d0);
#pragma unroll
      for (int jj = 0; jj < 8; ++jj) Vt[(d0 + jj) * 32 + vr] = v8[jj];
    }
    __syncthreads();

    // S = Q K^T for two 16-key sub-tiles
    float sv[2][4];
#pragma unroll
    for (int ks2 = 0; ks2 < 2; ++ks2) {
      f32x4 sacc = {0.f, 0.f, 0.f, 0.f};
#pragma unroll
      for (int kc = 0; kc < 4; ++kc) {
        bf16x8 kf = *(const bf16x8*)&Ks[(ks2 * 16 + lr) * 128 + kc * 32 + 8 * lc];
        sacc = MFMA(qf[kc], kf, sacc);
      }
#pragma unroll
      for (int r = 0; r < 4; ++r) {
        const int qg = q0 + w * 16 + lc * 4 + r;
        const int kg = k0 + ks2 * 16 + lr;
        sv[ks2][r] = (kg <= qg) ? sacc[r] * SCALE : -3e38f;
      }
    }

    // online softmax (shared max across the 32-key tile)
    float alpha[4];
#pragma unroll
    for (int r = 0; r < 4; ++r) {
      float pm = fmaxf(sv[0][r], sv[1][r]);
#pragma unroll
      for (int off = 1; off < 16; off <<= 1) pm = fmaxf(pm, __shfl_xor(pm, off, 64));
      const float mn = fmaxf(m_[r], pm);
      alpha[r] = __expf(m_[r] - mn);
      const float p0 = __expf(sv[0][r] - mn);
      const float p1 = __expf(sv[1][r] - mn);
      float ps = p0 + p1;
#pragma unroll
      for (int off = 1; off < 16; off <<= 1) ps += __shfl_xor(ps, off, 64);
      ls[r] = ls[r] * alpha[r] + ps;
      m_[r] = mn;
      Ps[w][(lc * 4 + r) * 32 + lr] = f2b(p0);
      Ps[w][(lc * 4 + r) * 32 + 16 + lr] = f2b(p1);
    }
#pragma unroll
    for (int dt = 0; dt < 8; ++dt)
#pragma unroll
      for (int r = 0; r < 4; ++r) O[dt][r] *= alpha[r];

    // O += P V  (P: A-op rows lr, k=8*lc..; V^T from LDS)
    bf16x8 ap = *(const bf16x8*)&Ps[w][lr * 32 + 8 * lc];
#pragma unroll
    for (int dt = 0; dt < 8; ++dt) {
      bf16x8 bv = *(const bf16x8*)&Vt[(dt * 16 + lr) * 32 + 8 * lc];
      O[dt] = MFMA(ap, bv, O[dt]);
    }
    __syncthreads();
  }

  float inv[4];
#pragma unroll
  for (int r = 0; r < 4; ++r) inv[r] = 1.f / ls[r];
#pragma unroll
  for (int dt = 0; dt < 8; ++dt)
#pragma unroll
    for (int r = 0; r < 4; ++r) {
      const int qg = q0 + w * 16 + lc * 4 + r;
      o[(size_t)(b * S + qg) * 4096 + h * 128 + dt * 16 + lr] = f2b(O[dt][r] * inv[r]);
    }
}

// ---------------------------------------------------------------- launch
extern "C" void kernel_launch(void* const* d_in, const int* in_sizes, int n_in,
                              void* d_out, int out_size, void* d_ws, size_t ws_size,
                              hipStream_t stream) {
  const int*   positions = (const int*)d_in[0];
  const float* hidden    = (const float*)d_in[1];
  const float* ln1       = (const float*)d_in[2];
  const float* ln2       = (const float*)d_in[3];
  const float* Wqkv      = (const float*)d_in[4];
  const float* bqkv      = (const float*)d_in[5];
  const float* Wo        = (const float*)d_in[6];
  const float* W1        = (const float*)d_in[7];
  const float* W2        = (const float*)d_in[8];
  const float* Wout      = (const float*)d_in[9];
  float* out = (float*)d_out;

  const int S = 2048, BS = 4096, D = 4096, FF = 11008, N3 = 12288;

  char* ws = (char*)d_ws;
  size_t off = 0;
  auto alloc = [&](size_t bytes) { void* p = ws + off; off += (bytes + 255) & ~(size_t)255; return p; };
  u16*   WT    = (u16*)alloc((size_t)N3 * D * 2);       // 100.7 MB, reused for every weight
  u16*   qkv   = (u16*)alloc((size_t)BS * N3 * 2);      // 100.7 MB
  u16*   slotH = (u16*)alloc((size_t)BS * D * 2);       //  33.6 MB (h / attn_out / h3)
  float* h2    = (float*)alloc((size_t)BS * D * 4);     //  67.1 MB
  u16*   slotG = (u16*)alloc((size_t)BS * FF * 2);      //  90.2 MB (G1 -> act in-place)
  float* tab   = (float*)alloc((size_t)2 * BS * 64 * 4);//   2.1 MB
  if (ws_size < off) return;  // leaves output poisoned -> clean diagnosable failure

  rope_table<<<(BS * 64 + 255) / 256, 256, 0, stream>>>(positions, tab, BS);

  // h = rmsnorm(hidden) ; qkv = h @ Wqkv + b
  transpose_cvt<<<dim3(N3 / 32, D / 32), dim3(32, 8), 0, stream>>>(Wqkv, WT, D, N3);
  rmsnorm_k<<<BS, 256, 0, stream>>>(hidden, ln1, slotH, D);
  gemm_bt<1><<<dim3(N3 / 128, BS / 128), 256, 0, stream>>>(slotH, WT, qkv, bqkv, nullptr, nullptr, BS, N3, D);
  rope_apply<<<(BS * 2048) / 256, 256, 0, stream>>>(qkv, tab, BS);

  // attention
  attn_kernel<<<dim3(S / 64, 64), 256, 0, stream>>>(qkv, slotH, S);

  // h2 = hidden + attn @ Wo
  transpose_cvt<<<dim3(D / 32, D / 32), dim3(32, 8), 0, stream>>>(Wo, WT, D, D);
  gemm_bt<2><<<dim3(D / 128, BS / 128), 256, 0, stream>>>(slotH, WT, h2, nullptr, hidden, nullptr, BS, D, D);

  // h3 = rmsnorm(h2) ; G1 = h3@W1 ; act = G1 * silu(h3@W2) ; out = h2 + act@Wout
  rmsnorm_k<<<BS, 256, 0, stream>>>(h2, ln2, slotH, D);
  transpose_cvt<<<dim3(FF / 32, D / 32), dim3(32, 8), 0, stream>>>(W1, WT, D, FF);
  gemm_bt<0><<<dim3(FF / 128, BS / 128), 256, 0, stream>>>(slotH, WT, slotG, nullptr, nullptr, nullptr, BS, FF, D);
  transpose_cvt<<<dim3(FF / 32, D / 32), dim3(32, 8), 0, stream>>>(W2, WT, D, FF);
  gemm_bt<3><<<dim3(FF / 128, BS / 128), 256, 0, stream>>>(slotH, WT, slotG, nullptr, nullptr, slotG, BS, FF, D);
  transpose_cvt<<<dim3(D / 32, FF / 32), dim3(32, 8), 0, stream>>>(Wout, WT, FF, D);
  gemm_bt<2><<<dim3(D / 128, BS / 128), 256, 0, stream>>>(slotG, WT, out, nullptr, h2, nullptr, BS, D, FF);
}

// Round 3
// 3293.660 us; speedup vs baseline: 1.2059x; 1.2059x over previous
//
#include <hip/hip_runtime.h>

typedef unsigned short u16;
typedef unsigned int   u32;
typedef __bf16 bf16x8 __attribute__((ext_vector_type(8)));
typedef float  f32x4  __attribute__((ext_vector_type(4)));
typedef unsigned short u16x4 __attribute__((ext_vector_type(4)));
typedef unsigned short u16x8 __attribute__((ext_vector_type(8)));

#define DEV __device__ __forceinline__

DEV u16 f2b(float f) {                      // f32 -> bf16 RNE
  u32 u = __builtin_bit_cast(u32, f);
  return (u16)((u + 0x7fffu + ((u >> 16) & 1u)) >> 16);
}
DEV float b2f(u16 h) { u32 u = ((u32)h) << 16; return __builtin_bit_cast(float, u); }

DEV void gload16(const void* g, void* l) {  // async global->LDS, 16B/lane
  __builtin_amdgcn_global_load_lds((__attribute__((address_space(1))) void*)(g),
                                   (__attribute__((address_space(3))) void*)(l),
                                   16, 0, 0);
}

DEV f32x4 MFMA(bf16x8 a, bf16x8 b, f32x4 c) {
  return __builtin_amdgcn_mfma_f32_16x16x32_bf16(a, b, c, 0, 0, 0);
}

// ---------------------------------------------------------------- transpose+cvt
__global__ __launch_bounds__(256) void transpose_cvt(const float* __restrict__ W,
                                                     u16* __restrict__ Wt,
                                                     int K, int N) {
  __shared__ float tile[32][33];
  const int n0 = blockIdx.x * 32, k0 = blockIdx.y * 32;
  const int tx = threadIdx.x, ty = threadIdx.y;  // 32 x 8
#pragma unroll
  for (int i = 0; i < 32; i += 8)
    tile[ty + i][tx] = W[(size_t)(k0 + ty + i) * N + n0 + tx];
  __syncthreads();
#pragma unroll
  for (int i = 0; i < 32; i += 8)
    Wt[(size_t)(n0 + ty + i) * K + k0 + tx] = f2b(tile[tx][ty + i]);
}

// ---------------------------------------------------------------- rmsnorm (f32 in, bf16 out), D=4096
__global__ __launch_bounds__(256) void rmsnorm_k(const float* __restrict__ x,
                                                 const float* __restrict__ w,
                                                 u16* __restrict__ o, int D) {
  const int row = blockIdx.x, tid = threadIdx.x;
  const float4* xr = (const float4*)(x + (size_t)row * D);
  const float4* wr = (const float4*)w;
  float4 v[4];
  float ss = 0.f;
#pragma unroll
  for (int i = 0; i < 4; ++i) {
    v[i] = xr[i * 256 + tid];
    ss += v[i].x * v[i].x + v[i].y * v[i].y + v[i].z * v[i].z + v[i].w * v[i].w;
  }
#pragma unroll
  for (int off = 1; off < 64; off <<= 1) ss += __shfl_xor(ss, off, 64);
  __shared__ float red[4];
  if ((tid & 63) == 0) red[tid >> 6] = ss;
  __syncthreads();
  const float tot = red[0] + red[1] + red[2] + red[3];
  const float sc = rsqrtf(tot / (float)D + 1e-6f);
  u16x4* orow = (u16x4*)(o + (size_t)row * D);
#pragma unroll
  for (int i = 0; i < 4; ++i) {
    float4 wv = wr[i * 256 + tid];
    u16x4 p;
    p[0] = f2b(v[i].x * sc * wv.x);
    p[1] = f2b(v[i].y * sc * wv.y);
    p[2] = f2b(v[i].z * sc * wv.z);
    p[3] = f2b(v[i].w * sc * wv.w);
    orow[i * 256 + tid] = p;
  }
}

// ---------------------------------------------------------------- RoPE table
__global__ __launch_bounds__(256) void rope_table(const int* __restrict__ positions,
                                                  float* __restrict__ tab, int BS) {
  const int idx = blockIdx.x * 256 + threadIdx.x;
  if (idx >= BS * 64) return;
  const int bs = idx >> 6, i = idx & 63;
  const float pos = (float)positions[bs];
  const float inv = __expf(-(float)i * (9.210340371976184f / 64.f));
  const float ang = pos * inv;
  float s, c;
  sincosf(ang, &s, &c);
  tab[idx] = c;
  tab[BS * 64 + idx] = s;
}

// ---------------------------------------------------------------- RoPE in-place on bf16 qkv [BS][12288]
__global__ __launch_bounds__(256) void rope_apply(u16* __restrict__ qkv,
                                                  const float* __restrict__ tab, int BS) {
  const int idx = blockIdx.x * 256 + threadIdx.x;  // (bs, h, i)
  if (idx >= BS * 2048) return;
  const int i = idx & 63, h = (idx >> 6) & 31, bs = idx >> 11;
  const float c = tab[bs * 64 + i];
  const float s = tab[(size_t)BS * 64 + bs * 64 + i];
  const size_t base = (size_t)bs * 12288 + h * 128 + i;
  float x1 = b2f(qkv[base]), x2 = b2f(qkv[base + 64]);
  qkv[base] = f2b(x1 * c - x2 * s);
  qkv[base + 64] = f2b(x2 * c + x1 * s);
  float y1 = b2f(qkv[base + 4096]), y2 = b2f(qkv[base + 4096 + 64]);
  qkv[base + 4096] = f2b(y1 * c - y2 * s);
  qkv[base + 4096 + 64] = f2b(y2 * c + y1 * s);
}

// ---------------------------------------------------------------- GEMM: C[M,N] = A[M,K] * Bt[N,K]^T (+epilogue)
template <int MODE>
__global__ __launch_bounds__(256) void gemm_bt(const u16* __restrict__ A,
                                               const u16* __restrict__ Bt,
                                               void* __restrict__ outp,
                                               const float* __restrict__ bias,
                                               const float* __restrict__ resid,
                                               const u16* __restrict__ g1,
                                               int M, int N, int K) {
  __shared__ __align__(16) u16 As[128 * 32];
  __shared__ __align__(16) u16 Bs[128 * 32];
  const int tid = threadIdx.x;
  const int w = tid >> 6, l = tid & 63;
  const int wm = w >> 1, wn = w & 1;
  const int lr = l & 15, lc = l >> 4;
  // XCD-aware bijective swizzle (T1): all grids here have nwg % 8 == 0
  const int gx = gridDim.x;
  const int nwg = gx * gridDim.y;
  const int orig = blockIdx.y * gx + blockIdx.x;
  const int wg = (orig & 7) * (nwg >> 3) + (orig >> 3);
  const int m0 = (wg / gx) * 128, n0 = (wg % gx) * 128;
  f32x4 acc[4][4] = {};
  const int nk = K >> 5;
  const int srow = tid >> 2, scol = (tid & 3) * 8;
  const u16* Ag = A + (size_t)(m0 + srow) * K + scol;
  const u16* Bg = Bt + (size_t)(n0 + srow) * K + scol;
  u16* AsB0 = &As[(w * 16) * 32];
  u16* AsB1 = &As[(64 + w * 16) * 32];
  u16* BsB0 = &Bs[(w * 16) * 32];
  u16* BsB1 = &Bs[(64 + w * 16) * 32];

  for (int kt = 0; kt < nk; ++kt) {
    const int k0 = kt << 5;
    gload16(Ag + k0, AsB0);
    gload16(Ag + (size_t)64 * K + k0, AsB1);
    gload16(Bg + k0, BsB0);
    gload16(Bg + (size_t)64 * K + k0, BsB1);
    __syncthreads();
    bf16x8 af[4], bfr[4];
#pragma unroll
    for (int f = 0; f < 4; ++f)
      af[f] = *(const bf16x8*)&As[(wm * 64 + f * 16 + lr) * 32 + 8 * lc];
#pragma unroll
    for (int f = 0; f < 4; ++f)
      bfr[f] = *(const bf16x8*)&Bs[(wn * 64 + f * 16 + lr) * 32 + 8 * lc];
#pragma unroll
    for (int i = 0; i < 4; ++i)
#pragma unroll
      for (int j = 0; j < 4; ++j) acc[i][j] = MFMA(af[i], bfr[j], acc[i][j]);
    __syncthreads();
  }

#pragma unroll
  for (int i = 0; i < 4; ++i) {
#pragma unroll
    for (int j = 0; j < 4; ++j) {
      const int gr = m0 + wm * 64 + i * 16 + lc * 4;
      const int gc = n0 + wn * 64 + j * 16 + lr;
#pragma unroll
      for (int r = 0; r < 4; ++r) {
        float v = acc[i][j][r];
        const size_t idx = (size_t)(gr + r) * N + gc;
        if constexpr (MODE == 0) {
          ((u16*)outp)[idx] = f2b(v);
        } else if constexpr (MODE == 1) {
          ((u16*)outp)[idx] = f2b(v + bias[gc]);
        } else if constexpr (MODE == 2) {
          ((float*)outp)[idx] = v + resid[idx];
        } else {
          const float g = b2f(g1[idx]);
          const float sv = v / (1.f + __expf(-v));
          ((u16*)outp)[idx] = f2b(g * sv);
        }
      }
    }
  }
}

// ---------------------------------------------------------------- flash attention (causal), HD=128, KVBLK=64
// All-plain-HIP LDS swizzles (no global_load_lds-swizzle, no tr-reads).
// K : Ks[k][d] at el = k*128 + (d ^ ((k&7)*8))          (16B-chunk XOR)
// V : Vt[d][k] at el = (d*64 + k) ^ ((d&7)*8)           (transposed, swizzled)
// P : Ps[w][q][k] at el = q*64 + (k ^ ((q&7)*8))        (per-wave)
__global__ __launch_bounds__(256) void attn_kernel(const u16* __restrict__ qkv,
                                                   u16* __restrict__ o, int S) {
  const int qtile = gridDim.x - 1 - blockIdx.x;   // largest-work blocks first
  const int bh = blockIdx.y;
  const int b = bh >> 5, h = bh & 31;
  const int q0 = qtile * 64;
  const int tid = threadIdx.x;
  const int w = tid >> 6, l = tid & 63;
  const int lr = l & 15, lc = l >> 4;
  const size_t RS = 12288;
  const float SCALE = 0.08838834764831845f;  // 128^-0.5

  __shared__ __align__(16) u16 Ks[64 * 128];
  __shared__ __align__(16) u16 Vt[128 * 64];
  __shared__ __align__(16) u16 Ps[4][16 * 64];

  // Q fragments (A-op): row = q0 + w*16 + lr, k-elems = kc*32 + 8*lc + j
  bf16x8 qf[4];
  {
    const u16* qp = qkv + (size_t)(b * S + q0 + w * 16 + lr) * RS + h * 128 + 8 * lc;
#pragma unroll
    for (int kc = 0; kc < 4; ++kc) qf[kc] = *(const bf16x8*)(qp + kc * 32);
  }

  float m_[4], ls[4];
  f32x4 O[8] = {};
#pragma unroll
  for (int r = 0; r < 4; ++r) { m_[r] = -3e38f; ls[r] = 0.f; }

  const int nkt = qtile + 1;
  for (int kt = 0; kt < nkt; ++kt) {
    const int k0 = kt * 64;
    // ---- stage K: coalesced loads, one swizzled ds_write_b128 per lane
#pragma unroll
    for (int it = 0; it < 4; ++it) {
      const int eid = it * 256 + tid;
      const int kr = eid >> 4, d0 = (eid & 15) * 8;
      u16x8 k8 = *(const u16x8*)(qkv + (size_t)(b * S + k0 + kr) * RS + 4096 + h * 128 + d0);
      *(u16x8*)&Ks[kr * 128 + (d0 ^ ((kr & 7) * 8))] = k8;
    }
    // ---- stage V transposed: lane owns row k0+l, chunk (it*4+w); bank-balanced scalar writes
#pragma unroll
    for (int it = 0; it < 4; ++it) {
      const int d0 = (it * 4 + w) * 8;
      u16x8 v8 = *(const u16x8*)(qkv + (size_t)(b * S + k0 + l) * RS + 8192 + h * 128 + d0);
#pragma unroll
      for (int jj = 0; jj < 8; ++jj) {
        const int d = d0 + jj;
        Vt[(d * 64 + l) ^ ((d & 7) * 8)] = v8[jj];
      }
    }
    __syncthreads();

    // ---- S = Q K^T (4 sub-tiles of 16 keys; skip fully-masked diagonal sub-tiles)
    const int nks = (kt == qtile) ? (w + 1) : 4;
    float sv[4][4];
#pragma unroll
    for (int ks = 0; ks < 4; ++ks) {
      if (ks < nks) {
        const int row = ks * 16 + lr;
        f32x4 sacc = {0.f, 0.f, 0.f, 0.f};
#pragma unroll
        for (int kc = 0; kc < 4; ++kc) {
          bf16x8 kf = *(const bf16x8*)&Ks[row * 128 + ((kc * 32 + 8 * lc) ^ ((lr & 7) * 8))];
          sacc = MFMA(qf[kc], kf, sacc);
        }
        const bool dm = (kt == qtile) && (ks == w);
#pragma unroll
        for (int r = 0; r < 4; ++r) {
          float x = sacc[r] * SCALE;
          if (dm) {
            const int kg = ks * 16 + lr, qg = w * 16 + lc * 4 + r;
            if (kg > qg) x = -3e38f;
          }
          sv[ks][r] = x;
        }
      } else {
#pragma unroll
        for (int r = 0; r < 4; ++r) sv[ks][r] = -3e38f;
      }
    }

    // ---- online softmax (row q = lc*4 + r; keys over ks x lr)
    float alpha[4];
#pragma unroll
    for (int r = 0; r < 4; ++r) {
      float pm = fmaxf(fmaxf(sv[0][r], sv[1][r]), fmaxf(sv[2][r], sv[3][r]));
#pragma unroll
      for (int off = 1; off < 16; off <<= 1) pm = fmaxf(pm, __shfl_xor(pm, off, 64));
      const float mn = fmaxf(m_[r], pm);
      alpha[r] = __expf(m_[r] - mn);
      m_[r] = mn;
    }
    float p[4][4];
#pragma unroll
    for (int ks = 0; ks < 4; ++ks)
#pragma unroll
      for (int r = 0; r < 4; ++r) {
        p[ks][r] = __expf(sv[ks][r] - m_[r]);
        const int q = lc * 4 + r, k = ks * 16 + lr;
        Ps[w][q * 64 + (k ^ ((q & 7) * 8))] = f2b(p[ks][r]);
      }
#pragma unroll
    for (int r = 0; r < 4; ++r) {
      float s = p[0][r] + p[1][r] + p[2][r] + p[3][r];
#pragma unroll
      for (int off = 1; off < 16; off <<= 1) s += __shfl_xor(s, off, 64);
      ls[r] = ls[r] * alpha[r] + s;
    }
#pragma unroll
    for (int dt = 0; dt < 8; ++dt)
#pragma unroll
      for (int r = 0; r < 4; ++r) O[dt][r] *= alpha[r];

    // ---- O += P V : all vector reads, conflict-free
#pragma unroll
    for (int half = 0; half < 2; ++half) {
      const bf16x8 ap = *(const bf16x8*)&Ps[w][lr * 64 + ((half * 32 + 8 * lc) ^ ((lr & 7) * 8))];
#pragma unroll
      for (int dt = 0; dt < 8; ++dt) {
        const int d = dt * 16 + lr;
        const bf16x8 bv = *(const bf16x8*)&Vt[d * 64 + ((half * 32 + 8 * lc) ^ ((d & 7) * 8))];
        O[dt] = MFMA(ap, bv, O[dt]);
      }
    }
    __syncthreads();
  }

  float inv[4];
#pragma unroll
  for (int r = 0; r < 4; ++r) inv[r] = 1.f / ls[r];
#pragma unroll
  for (int dt = 0; dt < 8; ++dt)
#pragma unroll
    for (int r = 0; r < 4; ++r) {
      const int qg = q0 + w * 16 + lc * 4 + r;
      o[(size_t)(b * S + qg) * 4096 + h * 128 + dt * 16 + lr] = f2b(O[dt][r] * inv[r]);
    }
}

// ---------------------------------------------------------------- launch
extern "C" void kernel_launch(void* const* d_in, const int* in_sizes, int n_in,
                              void* d_out, int out_size, void* d_ws, size_t ws_size,
                              hipStream_t stream) {
  const int*   positions = (const int*)d_in[0];
  const float* hidden    = (const float*)d_in[1];
  const float* ln1       = (const float*)d_in[2];
  const float* ln2       = (const float*)d_in[3];
  const float* Wqkv      = (const float*)d_in[4];
  const float* bqkv      = (const float*)d_in[5];
  const float* Wo        = (const float*)d_in[6];
  const float* W1        = (const float*)d_in[7];
  const float* W2        = (const float*)d_in[8];
  const float* Wout      = (const float*)d_in[9];
  float* out = (float*)d_out;

  const int S = 2048, BS = 4096, D = 4096, FF = 11008, N3 = 12288;

  char* ws = (char*)d_ws;
  size_t off = 0;
  auto alloc = [&](size_t bytes) { void* p = ws + off; off += (bytes + 255) & ~(size_t)255; return p; };
  u16*   WT    = (u16*)alloc((size_t)N3 * D * 2);       // reused for every weight
  u16*   qkv   = (u16*)alloc((size_t)BS * N3 * 2);
  u16*   slotH = (u16*)alloc((size_t)BS * D * 2);       // h / attn_out / h3
  float* h2    = (float*)alloc((size_t)BS * D * 4);
  u16*   slotG = (u16*)alloc((size_t)BS * FF * 2);      // G1 -> act in-place
  float* tab   = (float*)alloc((size_t)2 * BS * 64 * 4);
  if (ws_size < off) return;

  rope_table<<<(BS * 64 + 255) / 256, 256, 0, stream>>>(positions, tab, BS);

  // h = rmsnorm(hidden) ; qkv = h @ Wqkv + b
  transpose_cvt<<<dim3(N3 / 32, D / 32), dim3(32, 8), 0, stream>>>(Wqkv, WT, D, N3);
  rmsnorm_k<<<BS, 256, 0, stream>>>(hidden, ln1, slotH, D);
  gemm_bt<1><<<dim3(N3 / 128, BS / 128), 256, 0, stream>>>(slotH, WT, qkv, bqkv, nullptr, nullptr, BS, N3, D);
  rope_apply<<<(BS * 2048) / 256, 256, 0, stream>>>(qkv, tab, BS);

  // attention
  attn_kernel<<<dim3(S / 64, 64), 256, 0, stream>>>(qkv, slotH, S);

  // h2 = hidden + attn @ Wo
  transpose_cvt<<<dim3(D / 32, D / 32), dim3(32, 8), 0, stream>>>(Wo, WT, D, D);
  gemm_bt<2><<<dim3(D / 128, BS / 128), 256, 0, stream>>>(slotH, WT, h2, nullptr, hidden, nullptr, BS, D, D);

  // h3 = rmsnorm(h2) ; G1 = h3@W1 ; act = G1 * silu(h3@W2) ; out = h2 + act@Wout
  rmsnorm_k<<<BS, 256, 0, stream>>>(h2, ln2, slotH, D);
  transpose_cvt<<<dim3(FF / 32, D / 32), dim3(32, 8), 0, stream>>>(W1, WT, D, FF);
  gemm_bt<0><<<dim3(FF / 128, BS / 128), 256, 0, stream>>>(slotH, WT, slotG, nullptr, nullptr, nullptr, BS, FF, D);
  transpose_cvt<<<dim3(FF / 32, D / 32), dim3(32, 8), 0, stream>>>(W2, WT, D, FF);
  gemm_bt<3><<<dim3(FF / 128, BS / 128), 256, 0, stream>>>(slotH, WT, slotG, nullptr, nullptr, slotG, BS, FF, D);
  transpose_cvt<<<dim3(D / 32, FF / 32), dim3(32, 8), 0, stream>>>(Wout, WT, FF, D);
  gemm_bt<2><<<dim3(D / 128, BS / 128), 256, 0, stream>>>(slotG, WT, out, nullptr, h2, nullptr, BS, D, FF);
}

// Round 4
// 2607.855 us; speedup vs baseline: 1.5230x; 1.2630x over previous
//
#include <hip/hip_runtime.h>

typedef unsigned short u16;
typedef unsigned int   u32;
typedef __bf16 bf16x8 __attribute__((ext_vector_type(8)));
typedef float  f32x4  __attribute__((ext_vector_type(4)));
typedef unsigned short u16x4 __attribute__((ext_vector_type(4)));
typedef unsigned short u16x8 __attribute__((ext_vector_type(8)));

#define DEV __device__ __forceinline__

DEV u16 f2b(float f) {                      // f32 -> bf16 RNE
  u32 u = __builtin_bit_cast(u32, f);
  return (u16)((u + 0x7fffu + ((u >> 16) & 1u)) >> 16);
}
DEV float b2f(u16 h) { u32 u = ((u32)h) << 16; return __builtin_bit_cast(float, u); }

DEV void gload16(const void* g, void* l) {  // async global->LDS, 16B/lane
  __builtin_amdgcn_global_load_lds((__attribute__((address_space(1))) void*)(g),
                                   (__attribute__((address_space(3))) void*)(l),
                                   16, 0, 0);
}

DEV f32x4 MFMA(bf16x8 a, bf16x8 b, f32x4 c) {
  return __builtin_amdgcn_mfma_f32_16x16x32_bf16(a, b, c, 0, 0, 0);
}

// ---------------------------------------------------------------- transpose+cvt
__global__ __launch_bounds__(256) void transpose_cvt(const float* __restrict__ W,
                                                     u16* __restrict__ Wt,
                                                     int K, int N) {
  __shared__ float tile[32][33];
  const int n0 = blockIdx.x * 32, k0 = blockIdx.y * 32;
  const int tx = threadIdx.x, ty = threadIdx.y;  // 32 x 8
#pragma unroll
  for (int i = 0; i < 32; i += 8)
    tile[ty + i][tx] = W[(size_t)(k0 + ty + i) * N + n0 + tx];
  __syncthreads();
#pragma unroll
  for (int i = 0; i < 32; i += 8)
    Wt[(size_t)(n0 + ty + i) * K + k0 + tx] = f2b(tile[tx][ty + i]);
}

// ---------------------------------------------------------------- rmsnorm (f32 in, bf16 out), D=4096
__global__ __launch_bounds__(256) void rmsnorm_k(const float* __restrict__ x,
                                                 const float* __restrict__ w,
                                                 u16* __restrict__ o, int D) {
  const int row = blockIdx.x, tid = threadIdx.x;
  const float4* xr = (const float4*)(x + (size_t)row * D);
  const float4* wr = (const float4*)w;
  float4 v[4];
  float ss = 0.f;
#pragma unroll
  for (int i = 0; i < 4; ++i) {
    v[i] = xr[i * 256 + tid];
    ss += v[i].x * v[i].x + v[i].y * v[i].y + v[i].z * v[i].z + v[i].w * v[i].w;
  }
#pragma unroll
  for (int off = 1; off < 64; off <<= 1) ss += __shfl_xor(ss, off, 64);
  __shared__ float red[4];
  if ((tid & 63) == 0) red[tid >> 6] = ss;
  __syncthreads();
  const float tot = red[0] + red[1] + red[2] + red[3];
  const float sc = rsqrtf(tot / (float)D + 1e-6f);
  u16x4* orow = (u16x4*)(o + (size_t)row * D);
#pragma unroll
  for (int i = 0; i < 4; ++i) {
    float4 wv = wr[i * 256 + tid];
    u16x4 p;
    p[0] = f2b(v[i].x * sc * wv.x);
    p[1] = f2b(v[i].y * sc * wv.y);
    p[2] = f2b(v[i].z * sc * wv.z);
    p[3] = f2b(v[i].w * sc * wv.w);
    orow[i * 256 + tid] = p;
  }
}

// ---------------------------------------------------------------- RoPE table
__global__ __launch_bounds__(256) void rope_table(const int* __restrict__ positions,
                                                  float* __restrict__ tab, int BS) {
  const int idx = blockIdx.x * 256 + threadIdx.x;
  if (idx >= BS * 64) return;
  const int bs = idx >> 6, i = idx & 63;
  const float pos = (float)positions[bs];
  const float inv = __expf(-(float)i * (9.210340371976184f / 64.f));
  const float ang = pos * inv;
  float s, c;
  sincosf(ang, &s, &c);
  tab[idx] = c;
  tab[BS * 64 + idx] = s;
}

// ---------------------------------------------------------------- RoPE in-place on bf16 qkv [BS][12288]
__global__ __launch_bounds__(256) void rope_apply(u16* __restrict__ qkv,
                                                  const float* __restrict__ tab, int BS) {
  const int idx = blockIdx.x * 256 + threadIdx.x;  // (bs, h, i)
  if (idx >= BS * 2048) return;
  const int i = idx & 63, h = (idx >> 6) & 31, bs = idx >> 11;
  const float c = tab[bs * 64 + i];
  const float s = tab[(size_t)BS * 64 + bs * 64 + i];
  const size_t base = (size_t)bs * 12288 + h * 128 + i;
  float x1 = b2f(qkv[base]), x2 = b2f(qkv[base + 64]);
  qkv[base] = f2b(x1 * c - x2 * s);
  qkv[base + 64] = f2b(x2 * c + x1 * s);
  float y1 = b2f(qkv[base + 4096]), y2 = b2f(qkv[base + 4096 + 64]);
  qkv[base + 4096] = f2b(y1 * c - y2 * s);
  qkv[base + 4096 + 64] = f2b(y2 * c + y1 * s);
}

// ---------------------------------------------------------------- GEMM 256x256, BK=64, 8 waves, dbuf + counted vmcnt
// C[M,N] = A[M,K] * Bt[N,K]^T (+epilogue)
// MODE 0: bf16 out   1: bf16 + f32 bias[col]   2: f32 + f32 resid   3: bf16 g1*silu(acc)
template <int MODE>
__global__ __launch_bounds__(512, 2) void gemm256(const u16* __restrict__ A,
                                                  const u16* __restrict__ Bt,
                                                  void* __restrict__ outp,
                                                  const float* __restrict__ bias,
                                                  const float* __restrict__ resid,
                                                  const u16* __restrict__ g1,
                                                  int M, int N, int K) {
  __shared__ __align__(16) u16 As0[256 * 64], As1[256 * 64];
  __shared__ __align__(16) u16 Bs0[256 * 64], Bs1[256 * 64];   // 128 KiB total
  const int tid = threadIdx.x;
  const int wid = tid >> 6, l = tid & 63;
  const int wm = wid >> 2, wn = wid & 3;          // 2 x 4 waves, each owns 128x64
  const int lr = l & 15, lc = l >> 4;
  // T1 XCD-aware bijective swizzle (all grids: nwg % 8 == 0)
  const int gx = gridDim.x;
  const int nwg = gx * gridDim.y;
  const int orig = blockIdx.y * gx + blockIdx.x;
  const int wg = (orig & 7) * (nwg >> 3) + (orig >> 3);
  const int m0 = (wg / gx) * 256, n0 = (wg % gx) * 256;

  const int NT = K >> 6;                          // K-tiles of 64 (always even here)
  const int srow = wid * 8 + (l >> 3);            // staging: row within 64-row group
  const int scol = (l & 7) * 8;                   // 8 k-elems (16 B)
  const u16* Ag = A + (size_t)(m0 + srow) * K + scol;
  const u16* Bg = Bt + (size_t)(n0 + srow) * K + scol;

  f32x4 acc[8][4] = {};

  auto STAGE = [&](u16* asn, u16* bsn, int k0) {
#pragma unroll
    for (int c = 0; c < 4; ++c) {
      gload16(Ag + (size_t)(c * 64) * K + k0, asn + (c * 64 + wid * 8) * 64);
      gload16(Bg + (size_t)(c * 64) * K + k0, bsn + (c * 64 + wid * 8) * 64);
    }
  };

  auto ITER = [&](int t, const u16* as, const u16* bs, u16* asn, u16* bsn) {
    asm volatile("s_barrier" ::: "memory");        // prev reads of asn/bsn done chip-wide
    if (t + 1 < NT) {
      STAGE(asn, bsn, (t + 1) << 6);
      asm volatile("s_waitcnt vmcnt(8)" ::: "memory");  // tile-t loads landed; t+1 in flight
    } else {
      asm volatile("s_waitcnt vmcnt(0)" ::: "memory");
    }
    asm volatile("s_barrier" ::: "memory");        // all waves' tile-t loads visible
    bf16x8 bfr[4][2];
#pragma unroll
    for (int nf = 0; nf < 4; ++nf) {
      bfr[nf][0] = *(const bf16x8*)&bs[(wn * 64 + nf * 16 + lr) * 64 + lc * 8];
      bfr[nf][1] = *(const bf16x8*)&bs[(wn * 64 + nf * 16 + lr) * 64 + 32 + lc * 8];
    }
    __builtin_amdgcn_s_setprio(1);
#pragma unroll
    for (int mf = 0; mf < 8; ++mf) {
      const bf16x8 af0 = *(const bf16x8*)&as[(wm * 128 + mf * 16 + lr) * 64 + lc * 8];
      const bf16x8 af1 = *(const bf16x8*)&as[(wm * 128 + mf * 16 + lr) * 64 + 32 + lc * 8];
#pragma unroll
      for (int nf = 0; nf < 4; ++nf) {
        acc[mf][nf] = MFMA(af0, bfr[nf][0], acc[mf][nf]);
        acc[mf][nf] = MFMA(af1, bfr[nf][1], acc[mf][nf]);
      }
    }
    __builtin_amdgcn_s_setprio(0);
  };

  STAGE(As0, Bs0, 0);
  for (int t = 0; t < NT; t += 2) {
    ITER(t,     As0, Bs0, As1, Bs1);
    ITER(t + 1, As1, Bs1, As0, Bs0);
  }

#pragma unroll
  for (int mf = 0; mf < 8; ++mf) {
#pragma unroll
    for (int nf = 0; nf < 4; ++nf) {
      const int gr = m0 + wm * 128 + mf * 16 + lc * 4;
      const int gc = n0 + wn * 64 + nf * 16 + lr;
#pragma unroll
      for (int r = 0; r < 4; ++r) {
        float v = acc[mf][nf][r];
        const size_t idx = (size_t)(gr + r) * N + gc;
        if constexpr (MODE == 0) {
          ((u16*)outp)[idx] = f2b(v);
        } else if constexpr (MODE == 1) {
          ((u16*)outp)[idx] = f2b(v + bias[gc]);
        } else if constexpr (MODE == 2) {
          ((float*)outp)[idx] = v + resid[idx];
        } else {
          const float g = b2f(g1[idx]);
          const float sv = v / (1.f + __expf(-v));
          ((u16*)outp)[idx] = f2b(g * sv);
        }
      }
    }
  }
}

// ---------------------------------------------------------------- flash attention (causal), HD=128, KVBLK=64
// K : Ks[k][d] at el = k*128 + (d ^ ((k&7)*8))
// V : Vt[d][k] at el = (d*64 + k) ^ ((d&7)*8)
// P : Ps[w][q][k] at el = q*64 + (k ^ ((q&7)*8))
__global__ __launch_bounds__(256) void attn_kernel(const u16* __restrict__ qkv,
                                                   u16* __restrict__ o, int S) {
  const int qtile = gridDim.x - 1 - blockIdx.x;   // largest-work blocks first
  const int bh = blockIdx.y;
  const int b = bh >> 5, h = bh & 31;
  const int q0 = qtile * 64;
  const int tid = threadIdx.x;
  const int w = tid >> 6, l = tid & 63;
  const int lr = l & 15, lc = l >> 4;
  const size_t RS = 12288;
  const float SCALE = 0.08838834764831845f;  // 128^-0.5

  __shared__ __align__(16) u16 Ks[64 * 128];
  __shared__ __align__(16) u16 Vt[128 * 64];
  __shared__ __align__(16) u16 Ps[4][16 * 64];

  bf16x8 qf[4];
  {
    const u16* qp = qkv + (size_t)(b * S + q0 + w * 16 + lr) * RS + h * 128 + 8 * lc;
#pragma unroll
    for (int kc = 0; kc < 4; ++kc) qf[kc] = *(const bf16x8*)(qp + kc * 32);
  }

  float m_[4], ls[4];
  f32x4 O[8] = {};
#pragma unroll
  for (int r = 0; r < 4; ++r) { m_[r] = -3e38f; ls[r] = 0.f; }

  const int nkt = qtile + 1;
  for (int kt = 0; kt < nkt; ++kt) {
    const int k0 = kt * 64;
#pragma unroll
    for (int it = 0; it < 4; ++it) {
      const int eid = it * 256 + tid;
      const int kr = eid >> 4, d0 = (eid & 15) * 8;
      u16x8 k8 = *(const u16x8*)(qkv + (size_t)(b * S + k0 + kr) * RS + 4096 + h * 128 + d0);
      *(u16x8*)&Ks[kr * 128 + (d0 ^ ((kr & 7) * 8))] = k8;
    }
#pragma unroll
    for (int it = 0; it < 4; ++it) {
      const int d0 = (it * 4 + w) * 8;
      u16x8 v8 = *(const u16x8*)(qkv + (size_t)(b * S + k0 + l) * RS + 8192 + h * 128 + d0);
#pragma unroll
      for (int jj = 0; jj < 8; ++jj) {
        const int d = d0 + jj;
        Vt[(d * 64 + l) ^ ((d & 7) * 8)] = v8[jj];
      }
    }
    __syncthreads();

    const int nks = (kt == qtile) ? (w + 1) : 4;
    float sv[4][4];
#pragma unroll
    for (int ks = 0; ks < 4; ++ks) {
      if (ks < nks) {
        const int row = ks * 16 + lr;
        f32x4 sacc = {0.f, 0.f, 0.f, 0.f};
#pragma unroll
        for (int kc = 0; kc < 4; ++kc) {
          bf16x8 kf = *(const bf16x8*)&Ks[row * 128 + ((kc * 32 + 8 * lc) ^ ((lr & 7) * 8))];
          sacc = MFMA(qf[kc], kf, sacc);
        }
        const bool dm = (kt == qtile) && (ks == w);
#pragma unroll
        for (int r = 0; r < 4; ++r) {
          float x = sacc[r] * SCALE;
          if (dm) {
            const int kg = ks * 16 + lr, qg = w * 16 + lc * 4 + r;
            if (kg > qg) x = -3e38f;
          }
          sv[ks][r] = x;
        }
      } else {
#pragma unroll
        for (int r = 0; r < 4; ++r) sv[ks][r] = -3e38f;
      }
    }

    float alpha[4];
#pragma unroll
    for (int r = 0; r < 4; ++r) {
      float pm = fmaxf(fmaxf(sv[0][r], sv[1][r]), fmaxf(sv[2][r], sv[3][r]));
#pragma unroll
      for (int off = 1; off < 16; off <<= 1) pm = fmaxf(pm, __shfl_xor(pm, off, 64));
      const float mn = fmaxf(m_[r], pm);
      alpha[r] = __expf(m_[r] - mn);
      m_[r] = mn;
    }
    float p[4][4];
#pragma unroll
    for (int ks = 0; ks < 4; ++ks)
#pragma unroll
      for (int r = 0; r < 4; ++r) {
        p[ks][r] = __expf(sv[ks][r] - m_[r]);
        const int q = lc * 4 + r, k = ks * 16 + lr;
        Ps[w][q * 64 + (k ^ ((q & 7) * 8))] = f2b(p[ks][r]);
      }
#pragma unroll
    for (int r = 0; r < 4; ++r) {
      float s = p[0][r] + p[1][r] + p[2][r] + p[3][r];
#pragma unroll
      for (int off = 1; off < 16; off <<= 1) s += __shfl_xor(s, off, 64);
      ls[r] = ls[r] * alpha[r] + s;
    }
#pragma unroll
    for (int dt = 0; dt < 8; ++dt)
#pragma unroll
      for (int r = 0; r < 4; ++r) O[dt][r] *= alpha[r];

#pragma unroll
    for (int half = 0; half < 2; ++half) {
      const bf16x8 ap = *(const bf16x8*)&Ps[w][lr * 64 + ((half * 32 + 8 * lc) ^ ((lr & 7) * 8))];
#pragma unroll
      for (int dt = 0; dt < 8; ++dt) {
        const int d = dt * 16 + lr;
        const bf16x8 bv = *(const bf16x8*)&Vt[d * 64 + ((half * 32 + 8 * lc) ^ ((d & 7) * 8))];
        O[dt] = MFMA(ap, bv, O[dt]);
      }
    }
    __syncthreads();
  }

  float inv[4];
#pragma unroll
  for (int r = 0; r < 4; ++r) inv[r] = 1.f / ls[r];
#pragma unroll
  for (int dt = 0; dt < 8; ++dt)
#pragma unroll
    for (int r = 0; r < 4; ++r) {
      const int qg = q0 + w * 16 + lc * 4 + r;
      o[(size_t)(b * S + qg) * 4096 + h * 128 + dt * 16 + lr] = f2b(O[dt][r] * inv[r]);
    }
}

// ---------------------------------------------------------------- launch
extern "C" void kernel_launch(void* const* d_in, const int* in_sizes, int n_in,
                              void* d_out, int out_size, void* d_ws, size_t ws_size,
                              hipStream_t stream) {
  const int*   positions = (const int*)d_in[0];
  const float* hidden    = (const float*)d_in[1];
  const float* ln1       = (const float*)d_in[2];
  const float* ln2       = (const float*)d_in[3];
  const float* Wqkv      = (const float*)d_in[4];
  const float* bqkv      = (const float*)d_in[5];
  const float* Wo        = (const float*)d_in[6];
  const float* W1        = (const float*)d_in[7];
  const float* W2        = (const float*)d_in[8];
  const float* Wout      = (const float*)d_in[9];
  float* out = (float*)d_out;

  const int S = 2048, BS = 4096, D = 4096, FF = 11008, N3 = 12288;

  char* ws = (char*)d_ws;
  size_t off = 0;
  auto alloc = [&](size_t bytes) { void* p = ws + off; off += (bytes + 255) & ~(size_t)255; return p; };
  u16*   WT    = (u16*)alloc((size_t)N3 * D * 2);       // reused for every weight
  u16*   qkv   = (u16*)alloc((size_t)BS * N3 * 2);
  u16*   slotH = (u16*)alloc((size_t)BS * D * 2);       // h / attn_out / h3
  float* h2    = (float*)alloc((size_t)BS * D * 4);
  u16*   slotG = (u16*)alloc((size_t)BS * FF * 2);      // G1 -> act in-place
  float* tab   = (float*)alloc((size_t)2 * BS * 64 * 4);
  if (ws_size < off) return;

  rope_table<<<(BS * 64 + 255) / 256, 256, 0, stream>>>(positions, tab, BS);

  // h = rmsnorm(hidden) ; qkv = h @ Wqkv + b
  transpose_cvt<<<dim3(N3 / 32, D / 32), dim3(32, 8), 0, stream>>>(Wqkv, WT, D, N3);
  rmsnorm_k<<<BS, 256, 0, stream>>>(hidden, ln1, slotH, D);
  gemm256<1><<<dim3(N3 / 256, BS / 256), 512, 0, stream>>>(slotH, WT, qkv, bqkv, nullptr, nullptr, BS, N3, D);
  rope_apply<<<(BS * 2048) / 256, 256, 0, stream>>>(qkv, tab, BS);

  // attention
  attn_kernel<<<dim3(S / 64, 64), 256, 0, stream>>>(qkv, slotH, S);

  // h2 = hidden + attn @ Wo
  transpose_cvt<<<dim3(D / 32, D / 32), dim3(32, 8), 0, stream>>>(Wo, WT, D, D);
  gemm256<2><<<dim3(D / 256, BS / 256), 512, 0, stream>>>(slotH, WT, h2, nullptr, hidden, nullptr, BS, D, D);

  // h3 = rmsnorm(h2) ; G1 = h3@W1 ; act = G1 * silu(h3@W2) ; out = h2 + act@Wout
  rmsnorm_k<<<BS, 256, 0, stream>>>(h2, ln2, slotH, D);
  transpose_cvt<<<dim3(FF / 32, D / 32), dim3(32, 8), 0, stream>>>(W1, WT, D, FF);
  gemm256<0><<<dim3(FF / 256, BS / 256), 512, 0, stream>>>(slotH, WT, slotG, nullptr, nullptr, nullptr, BS, FF, D);
  transpose_cvt<<<dim3(FF / 32, D / 32), dim3(32, 8), 0, stream>>>(W2, WT, D, FF);
  gemm256<3><<<dim3(FF / 256, BS / 256), 512, 0, stream>>>(slotH, WT, slotG, nullptr, nullptr, slotG, BS, FF, D);
  transpose_cvt<<<dim3(D / 32, FF / 32), dim3(32, 8), 0, stream>>>(Wout, WT, FF, D);
  gemm256<2><<<dim3(D / 256, BS / 256), 512, 0, stream>>>(slotG, WT, out, nullptr, h2, nullptr, BS, D, FF);
}

// Round 6
// 2361.011 us; speedup vs baseline: 1.6822x; 1.1046x over previous
//
#include <hip/hip_runtime.h>

typedef unsigned short u16;
typedef unsigned int   u32;
typedef __bf16 bf16x8 __attribute__((ext_vector_type(8)));
typedef float  f32x4  __attribute__((ext_vector_type(4)));
typedef unsigned short u16x4 __attribute__((ext_vector_type(4)));
typedef unsigned short u16x8 __attribute__((ext_vector_type(8)));

#define DEV __device__ __forceinline__

DEV u16 f2b(float f) {                      // f32 -> bf16 RNE
  u32 u = __builtin_bit_cast(u32, f);
  return (u16)((u + 0x7fffu + ((u >> 16) & 1u)) >> 16);
}
DEV float b2f(u16 h) { u32 u = ((u32)h) << 16; return __builtin_bit_cast(float, u); }

DEV void gload16(const void* g, void* l) {  // async global->LDS, 16B/lane
  __builtin_amdgcn_global_load_lds((__attribute__((address_space(1))) void*)(g),
                                   (__attribute__((address_space(3))) void*)(l),
                                   16, 0, 0);
}

DEV f32x4 MFMA(bf16x8 a, bf16x8 b, f32x4 c) {
  return __builtin_amdgcn_mfma_f32_16x16x32_bf16(a, b, c, 0, 0, 0);
}

// ---------------------------------------------------------------- transpose+cvt
__global__ __launch_bounds__(256) void transpose_cvt(const float* __restrict__ W,
                                                     u16* __restrict__ Wt,
                                                     int K, int N) {
  __shared__ float tile[32][33];
  const int n0 = blockIdx.x * 32, k0 = blockIdx.y * 32;
  const int tx = threadIdx.x, ty = threadIdx.y;  // 32 x 8
#pragma unroll
  for (int i = 0; i < 32; i += 8)
    tile[ty + i][tx] = W[(size_t)(k0 + ty + i) * N + n0 + tx];
  __syncthreads();
#pragma unroll
  for (int i = 0; i < 32; i += 8)
    Wt[(size_t)(n0 + ty + i) * K + k0 + tx] = f2b(tile[tx][ty + i]);
}

// ---------------------------------------------------------------- rmsnorm (f32 in, bf16 out), D=4096
__global__ __launch_bounds__(256) void rmsnorm_k(const float* __restrict__ x,
                                                 const float* __restrict__ w,
                                                 u16* __restrict__ o, int D) {
  const int row = blockIdx.x, tid = threadIdx.x;
  const float4* xr = (const float4*)(x + (size_t)row * D);
  const float4* wr = (const float4*)w;
  float4 v[4];
  float ss = 0.f;
#pragma unroll
  for (int i = 0; i < 4; ++i) {
    v[i] = xr[i * 256 + tid];
    ss += v[i].x * v[i].x + v[i].y * v[i].y + v[i].z * v[i].z + v[i].w * v[i].w;
  }
#pragma unroll
  for (int off = 1; off < 64; off <<= 1) ss += __shfl_xor(ss, off, 64);
  __shared__ float red[4];
  if ((tid & 63) == 0) red[tid >> 6] = ss;
  __syncthreads();
  const float tot = red[0] + red[1] + red[2] + red[3];
  const float sc = rsqrtf(tot / (float)D + 1e-6f);
  u16x4* orow = (u16x4*)(o + (size_t)row * D);
#pragma unroll
  for (int i = 0; i < 4; ++i) {
    float4 wv = wr[i * 256 + tid];
    u16x4 p;
    p[0] = f2b(v[i].x * sc * wv.x);
    p[1] = f2b(v[i].y * sc * wv.y);
    p[2] = f2b(v[i].z * sc * wv.z);
    p[3] = f2b(v[i].w * sc * wv.w);
    orow[i * 256 + tid] = p;
  }
}

// ---------------------------------------------------------------- RoPE table
__global__ __launch_bounds__(256) void rope_table(const int* __restrict__ positions,
                                                  float* __restrict__ tab, int BS) {
  const int idx = blockIdx.x * 256 + threadIdx.x;
  if (idx >= BS * 64) return;
  const int bs = idx >> 6, i = idx & 63;
  const float pos = (float)positions[bs];
  const float inv = __expf(-(float)i * (9.210340371976184f / 64.f));
  const float ang = pos * inv;
  float s, c;
  sincosf(ang, &s, &c);
  tab[idx] = c;
  tab[BS * 64 + idx] = s;
}

// ---------------------------------------------------------------- RoPE in-place on bf16 qkv [BS][12288]
__global__ __launch_bounds__(256) void rope_apply(u16* __restrict__ qkv,
                                                  const float* __restrict__ tab, int BS) {
  const int idx = blockIdx.x * 256 + threadIdx.x;  // (bs, h, i)
  if (idx >= BS * 2048) return;
  const int i = idx & 63, h = (idx >> 6) & 31, bs = idx >> 11;
  const float c = tab[bs * 64 + i];
  const float s = tab[(size_t)BS * 64 + bs * 64 + i];
  const size_t base = (size_t)bs * 12288 + h * 128 + i;
  float x1 = b2f(qkv[base]), x2 = b2f(qkv[base + 64]);
  qkv[base] = f2b(x1 * c - x2 * s);
  qkv[base + 64] = f2b(x2 * c + x1 * s);
  float y1 = b2f(qkv[base + 4096]), y2 = b2f(qkv[base + 4096 + 64]);
  qkv[base + 4096] = f2b(y1 * c - y2 * s);
  qkv[base + 4096 + 64] = f2b(y2 * c + y1 * s);
}

// ---------------------------------------------------------------- GEMM 256x256, BK=64, 8 waves, dbuf + counted vmcnt
// T2 LDS swizzle: logical chunk (row, cc) stored at chunk (row, cc ^ (row&7));
// achieved with LINEAR gload_lds dest + inverse-permuted per-lane global source
// (rule 21 / m173: permutation stays inside each 128-B row segment -> coalescing kept).
// MODE 0: bf16 out   1: bf16 + f32 bias[col]   2: f32 + f32 resid   3: bf16 g1*silu(acc)
template <int MODE>
__global__ __launch_bounds__(512, 2) void gemm256(const u16* __restrict__ A,
                                                  const u16* __restrict__ Bt,
                                                  void* __restrict__ outp,
                                                  const float* __restrict__ bias,
                                                  const float* __restrict__ resid,
                                                  const u16* __restrict__ g1,
                                                  int M, int N, int K) {
  __shared__ __align__(16) u16 As0[256 * 64], As1[256 * 64];
  __shared__ __align__(16) u16 Bs0[256 * 64], Bs1[256 * 64];   // 128 KiB total
  const int tid = threadIdx.x;
  const int wid = tid >> 6, l = tid & 63;
  const int wm = wid >> 2, wn = wid & 3;          // 2 x 4 waves, each owns 128x64
  const int lr = l & 15, lc = l >> 4;
  // T1 XCD-aware bijective swizzle (all grids: nwg % 8 == 0)
  const int gx = gridDim.x;
  const int nwg = gx * gridDim.y;
  const int orig = blockIdx.y * gx + blockIdx.x;
  const int wg = (orig & 7) * (nwg >> 3) + (orig >> 3);
  const int m0 = (wg / gx) * 256, n0 = (wg % gx) * 256;

  const int NT = K >> 6;                          // K-tiles of 64 (always even here)
  const int srow = wid * 8 + (l >> 3);            // staging: row within 64-row group
  const int scol = ((l & 7) ^ ((l >> 3) & 7)) * 8;  // inverse-swizzled source chunk
  const u16* Ag = A + (size_t)(m0 + srow) * K + scol;
  const u16* Bg = Bt + (size_t)(n0 + srow) * K + scol;

  f32x4 acc[8][4] = {};

  auto STAGE = [&](u16* asn, u16* bsn, int k0) {
#pragma unroll
    for (int c = 0; c < 4; ++c) {
      gload16(Ag + (size_t)(c * 64) * K + k0, asn + (c * 64 + wid * 8) * 64);
      gload16(Bg + (size_t)(c * 64) * K + k0, bsn + (c * 64 + wid * 8) * 64);
    }
  };

  auto ITER = [&](int t, const u16* as, const u16* bs, u16* asn, u16* bsn) {
    asm volatile("s_barrier" ::: "memory");        // prev reads of asn/bsn done chip-wide
    if (t + 1 < NT) {
      STAGE(asn, bsn, (t + 1) << 6);
      asm volatile("s_waitcnt vmcnt(8)" ::: "memory");  // tile-t loads landed; t+1 in flight
    } else {
      asm volatile("s_waitcnt vmcnt(0)" ::: "memory");
    }
    asm volatile("s_barrier" ::: "memory");        // all waves' tile-t loads visible
    bf16x8 bfr[4][2];
#pragma unroll
    for (int nf = 0; nf < 4; ++nf) {
      const int br = wn * 64 + nf * 16 + lr;
      const int bx = (br & 7) * 8;
      bfr[nf][0] = *(const bf16x8*)&bs[br * 64 + ((lc * 8) ^ bx)];
      bfr[nf][1] = *(const bf16x8*)&bs[br * 64 + ((32 + lc * 8) ^ bx)];
    }
    __builtin_amdgcn_s_setprio(1);
#pragma unroll
    for (int mf = 0; mf < 8; ++mf) {
      const int ar = wm * 128 + mf * 16 + lr;
      const int ax = (ar & 7) * 8;
      const bf16x8 af0 = *(const bf16x8*)&as[ar * 64 + ((lc * 8) ^ ax)];
      const bf16x8 af1 = *(const bf16x8*)&as[ar * 64 + ((32 + lc * 8) ^ ax)];
#pragma unroll
      for (int nf = 0; nf < 4; ++nf) {
        acc[mf][nf] = MFMA(af0, bfr[nf][0], acc[mf][nf]);
        acc[mf][nf] = MFMA(af1, bfr[nf][1], acc[mf][nf]);
      }
    }
    __builtin_amdgcn_s_setprio(0);
  };

  STAGE(As0, Bs0, 0);
  for (int t = 0; t < NT; t += 2) {
    ITER(t,     As0, Bs0, As1, Bs1);
    ITER(t + 1, As1, Bs1, As0, Bs0);
  }

#pragma unroll
  for (int mf = 0; mf < 8; ++mf) {
#pragma unroll
    for (int nf = 0; nf < 4; ++nf) {
      const int gr = m0 + wm * 128 + mf * 16 + lc * 4;
      const int gc = n0 + wn * 64 + nf * 16 + lr;
#pragma unroll
      for (int r = 0; r < 4; ++r) {
        float v = acc[mf][nf][r];
        const size_t idx = (size_t)(gr + r) * N + gc;
        if constexpr (MODE == 0) {
          ((u16*)outp)[idx] = f2b(v);
        } else if constexpr (MODE == 1) {
          ((u16*)outp)[idx] = f2b(v + bias[gc]);
        } else if constexpr (MODE == 2) {
          ((float*)outp)[idx] = v + resid[idx];
        } else {
          const float g = b2f(g1[idx]);
          const float sv = v / (1.f + __expf(-v));
          ((u16*)outp)[idx] = f2b(g * sv);
        }
      }
    }
  }
}

// ---------------------------------------------------------------- flash attention (causal), HD=128, KVBLK=64
// K : Ks[k][d] at el = k*128 + (d ^ ((k&7)*8))
// V : Vt[d][k] at el = (d*64 + k) ^ ((d&7)*8)
// P : Ps[w][q][k] at el = q*64 + (k ^ ((q&7)*8))
__global__ __launch_bounds__(256) void attn_kernel(const u16* __restrict__ qkv,
                                                   u16* __restrict__ o, int S) {
  const int qtile = gridDim.x - 1 - blockIdx.x;   // largest-work blocks first
  const int bh = blockIdx.y;
  const int b = bh >> 5, h = bh & 31;
  const int q0 = qtile * 64;
  const int tid = threadIdx.x;
  const int w = tid >> 6, l = tid & 63;
  const int lr = l & 15, lc = l >> 4;
  const size_t RS = 12288;
  const float SCALE = 0.08838834764831845f;  // 128^-0.5

  __shared__ __align__(16) u16 Ks[64 * 128];
  __shared__ __align__(16) u16 Vt[128 * 64];
  __shared__ __align__(16) u16 Ps[4][16 * 64];

  bf16x8 qf[4];
  {
    const u16* qp = qkv + (size_t)(b * S + q0 + w * 16 + lr) * RS + h * 128 + 8 * lc;
#pragma unroll
    for (int kc = 0; kc < 4; ++kc) qf[kc] = *(const bf16x8*)(qp + kc * 32);
  }

  float m_[4], ls[4];
  f32x4 O[8] = {};
#pragma unroll
  for (int r = 0; r < 4; ++r) { m_[r] = -3e38f; ls[r] = 0.f; }

  const int nkt = qtile + 1;
  for (int kt = 0; kt < nkt; ++kt) {
    const int k0 = kt * 64;
#pragma unroll
    for (int it = 0; it < 4; ++it) {
      const int eid = it * 256 + tid;
      const int kr = eid >> 4, d0 = (eid & 15) * 8;
      u16x8 k8 = *(const u16x8*)(qkv + (size_t)(b * S + k0 + kr) * RS + 4096 + h * 128 + d0);
      *(u16x8*)&Ks[kr * 128 + (d0 ^ ((kr & 7) * 8))] = k8;
    }
#pragma unroll
    for (int it = 0; it < 4; ++it) {
      const int d0 = (it * 4 + w) * 8;
      u16x8 v8 = *(const u16x8*)(qkv + (size_t)(b * S + k0 + l) * RS + 8192 + h * 128 + d0);
#pragma unroll
      for (int jj = 0; jj < 8; ++jj) {
        const int d = d0 + jj;
        Vt[(d * 64 + l) ^ ((d & 7) * 8)] = v8[jj];
      }
    }
    __syncthreads();

    const int nks = (kt == qtile) ? (w + 1) : 4;
    float sv[4][4];
#pragma unroll
    for (int ks = 0; ks < 4; ++ks) {
      if (ks < nks) {
        const int row = ks * 16 + lr;
        f32x4 sacc = {0.f, 0.f, 0.f, 0.f};
#pragma unroll
        for (int kc = 0; kc < 4; ++kc) {
          bf16x8 kf = *(const bf16x8*)&Ks[row * 128 + ((kc * 32 + 8 * lc) ^ ((lr & 7) * 8))];
          sacc = MFMA(qf[kc], kf, sacc);
        }
        const bool dm = (kt == qtile) && (ks == w);
#pragma unroll
        for (int r = 0; r < 4; ++r) {
          float x = sacc[r] * SCALE;
          if (dm) {
            const int kg = ks * 16 + lr, qg = w * 16 + lc * 4 + r;
            if (kg > qg) x = -3e38f;
          }
          sv[ks][r] = x;
        }
      } else {
#pragma unroll
        for (int r = 0; r < 4; ++r) sv[ks][r] = -3e38f;
      }
    }

    float alpha[4];
#pragma unroll
    for (int r = 0; r < 4; ++r) {
      float pm = fmaxf(fmaxf(sv[0][r], sv[1][r]), fmaxf(sv[2][r], sv[3][r]));
#pragma unroll
      for (int off = 1; off < 16; off <<= 1) pm = fmaxf(pm, __shfl_xor(pm, off, 64));
      const float mn = fmaxf(m_[r], pm);
      alpha[r] = __expf(m_[r] - mn);
      m_[r] = mn;
    }
    float p[4][4];
#pragma unroll
    for (int ks = 0; ks < 4; ++ks)
#pragma unroll
      for (int r = 0; r < 4; ++r) {
        p[ks][r] = __expf(sv[ks][r] - m_[r]);
        const int q = lc * 4 + r, k = ks * 16 + lr;
        Ps[w][q * 64 + (k ^ ((q & 7) * 8))] = f2b(p[ks][r]);
      }
#pragma unroll
    for (int r = 0; r < 4; ++r) {
      float s = p[0][r] + p[1][r] + p[2][r] + p[3][r];
#pragma unroll
      for (int off = 1; off < 16; off <<= 1) s += __shfl_xor(s, off, 64);
      ls[r] = ls[r] * alpha[r] + s;
    }
#pragma unroll
    for (int dt = 0; dt < 8; ++dt)
#pragma unroll
      for (int r = 0; r < 4; ++r) O[dt][r] *= alpha[r];

#pragma unroll
    for (int half = 0; half < 2; ++half) {
      const bf16x8 ap = *(const bf16x8*)&Ps[w][lr * 64 + ((half * 32 + 8 * lc) ^ ((lr & 7) * 8))];
#pragma unroll
      for (int dt = 0; dt < 8; ++dt) {
        const int d = dt * 16 + lr;
        const bf16x8 bv = *(const bf16x8*)&Vt[d * 64 + ((half * 32 + 8 * lc) ^ ((d & 7) * 8))];
        O[dt] = MFMA(ap, bv, O[dt]);
      }
    }
    __syncthreads();
  }

  float inv[4];
#pragma unroll
  for (int r = 0; r < 4; ++r) inv[r] = 1.f / ls[r];
#pragma unroll
  for (int dt = 0; dt < 8; ++dt)
#pragma unroll
    for (int r = 0; r < 4; ++r) {
      const int qg = q0 + w * 16 + lc * 4 + r;
      o[(size_t)(b * S + qg) * 4096 + h * 128 + dt * 16 + lr] = f2b(O[dt][r] * inv[r]);
    }
}

// ---------------------------------------------------------------- launch
extern "C" void kernel_launch(void* const* d_in, const int* in_sizes, int n_in,
                              void* d_out, int out_size, void* d_ws, size_t ws_size,
                              hipStream_t stream) {
  const int*   positions = (const int*)d_in[0];
  const float* hidden    = (const float*)d_in[1];
  const float* ln1       = (const float*)d_in[2];
  const float* ln2       = (const float*)d_in[3];
  const float* Wqkv      = (const float*)d_in[4];
  const float* bqkv      = (const float*)d_in[5];
  const float* Wo        = (const float*)d_in[6];
  const float* W1        = (const float*)d_in[7];
  const float* W2        = (const float*)d_in[8];
  const float* Wout      = (const float*)d_in[9];
  float* out = (float*)d_out;

  const int S = 2048, BS = 4096, D = 4096, FF = 11008, N3 = 12288;

  char* ws = (char*)d_ws;
  size_t off = 0;
  auto alloc = [&](size_t bytes) { void* p = ws + off; off += (bytes + 255) & ~(size_t)255; return p; };
  u16*   WT    = (u16*)alloc((size_t)N3 * D * 2);       // reused for every weight
  u16*   qkv   = (u16*)alloc((size_t)BS * N3 * 2);
  u16*   slotH = (u16*)alloc((size_t)BS * D * 2);       // h / attn_out / h3
  float* h2    = (float*)alloc((size_t)BS * D * 4);
  u16*   slotG = (u16*)alloc((size_t)BS * FF * 2);      // G1 -> act in-place
  float* tab   = (float*)alloc((size_t)2 * BS * 64 * 4);
  if (ws_size < off) return;

  rope_table<<<(BS * 64 + 255) / 256, 256, 0, stream>>>(positions, tab, BS);

  // h = rmsnorm(hidden) ; qkv = h @ Wqkv + b
  transpose_cvt<<<dim3(N3 / 32, D / 32), dim3(32, 8), 0, stream>>>(Wqkv, WT, D, N3);
  rmsnorm_k<<<BS, 256, 0, stream>>>(hidden, ln1, slotH, D);
  gemm256<1><<<dim3(N3 / 256, BS / 256), 512, 0, stream>>>(slotH, WT, qkv, bqkv, nullptr, nullptr, BS, N3, D);
  rope_apply<<<(BS * 2048) / 256, 256, 0, stream>>>(qkv, tab, BS);

  // attention
  attn_kernel<<<dim3(S / 64, 64), 256, 0, stream>>>(qkv, slotH, S);

  // h2 = hidden + attn @ Wo
  transpose_cvt<<<dim3(D / 32, D / 32), dim3(32, 8), 0, stream>>>(Wo, WT, D, D);
  gemm256<2><<<dim3(D / 256, BS / 256), 512, 0, stream>>>(slotH, WT, h2, nullptr, hidden, nullptr, BS, D, D);

  // h3 = rmsnorm(h2) ; G1 = h3@W1 ; act = G1 * silu(h3@W2) ; out = h2 + act@Wout
  rmsnorm_k<<<BS, 256, 0, stream>>>(h2, ln2, slotH, D);
  transpose_cvt<<<dim3(FF / 32, D / 32), dim3(32, 8), 0, stream>>>(W1, WT, D, FF);
  gemm256<0><<<dim3(FF / 256, BS / 256), 512, 0, stream>>>(slotH, WT, slotG, nullptr, nullptr, nullptr, BS, FF, D);
  transpose_cvt<<<dim3(FF / 32, D / 32), dim3(32, 8), 0, stream>>>(W2, WT, D, FF);
  gemm256<3><<<dim3(FF / 256, BS / 256), 512, 0, stream>>>(slotH, WT, slotG, nullptr, nullptr, slotG, BS, FF, D);
  transpose_cvt<<<dim3(D / 32, FF / 32), dim3(32, 8), 0, stream>>>(Wout, WT, FF, D);
  gemm256<2><<<dim3(D / 256, BS / 256), 512, 0, stream>>>(slotG, WT, out, nullptr, h2, nullptr, BS, D, FF);
}